// Round 2
// baseline (188.022 us; speedup 1.0000x reference)
//
#include <hip/hip_runtime.h>

#define B 64
#define C 1024
#define HW 4096          // 64*64
#define E 16
#define TOPK 2

// ---------------------------------------------------------------------------
// Kernel 1: pooled[b,c] = mean over HW of x[b,c,:,:]
// One block (256 threads) per row of 4096 floats. float4 coalesced loads.
// ---------------------------------------------------------------------------
__global__ __launch_bounds__(256) void pool_kernel(const float* __restrict__ x,
                                                   float* __restrict__ pooled) {
    const int row = blockIdx.x;                   // 0 .. B*C-1
    const float4* xr = reinterpret_cast<const float4*>(x + (size_t)row * HW);
    const int t = threadIdx.x;                    // 0..255

    float s = 0.f;
#pragma unroll
    for (int k = 0; k < 4; ++k) {                 // 4 * 256 float4 = 4096 floats
        float4 v = xr[t + k * 256];
        s += (v.x + v.y) + (v.z + v.w);
    }

    // wave (64-lane) reduction
#pragma unroll
    for (int off = 32; off > 0; off >>= 1)
        s += __shfl_down(s, off, 64);

    __shared__ float ws[4];
    const int lane = t & 63, wid = t >> 6;
    if (lane == 0) ws[wid] = s;
    __syncthreads();
    if (t == 0) {
        float tot = (ws[0] + ws[1]) + (ws[2] + ws[3]);
        pooled[row] = tot * (1.0f / HW);
    }
}

// ---------------------------------------------------------------------------
// Kernel 2: per-batch gating: logits = pooled @ gate_w^T + gate_b,
// clip, +expert_bias, softmax, clip, top-2 (jax tie-break: lowest index),
// renormalize. Writes probs -> out[0:128], indices(float) -> out[128:256].
// ---------------------------------------------------------------------------
__global__ __launch_bounds__(256) void gate_kernel(const float* __restrict__ pooled,
                                                   const float* __restrict__ gate_w,
                                                   const float* __restrict__ gate_b,
                                                   const float* __restrict__ expert_bias,
                                                   float* __restrict__ out) {
    const int b = blockIdx.x;                     // 0..B-1
    const int t = threadIdx.x;                    // 0..255

    float acc[E];
#pragma unroll
    for (int e = 0; e < E; ++e) acc[e] = 0.f;

    const float* pr = pooled + b * C;
    for (int c = t; c < C; c += 256) {            // 4 iterations
        float p = pr[c];
#pragma unroll
        for (int e = 0; e < E; ++e)
            acc[e] += p * gate_w[e * C + c];
    }

    __shared__ float red[E][4];
    const int lane = t & 63, wid = t >> 6;
#pragma unroll
    for (int e = 0; e < E; ++e) {
        float v = acc[e];
#pragma unroll
        for (int off = 32; off > 0; off >>= 1)
            v += __shfl_down(v, off, 64);
        if (lane == 0) red[e][wid] = v;
    }
    __syncthreads();

    if (t == 0) {
        float logit[E];
        float mx = -1e30f;
#pragma unroll
        for (int e = 0; e < E; ++e) {
            float l = (red[e][0] + red[e][1]) + (red[e][2] + red[e][3]) + gate_b[e];
            l = fminf(fmaxf(l, -10.0f), 10.0f);   // clip logits
            l += expert_bias[e];
            logit[e] = l;
            mx = fmaxf(mx, l);
        }
        float p[E];
        float sum = 0.f;
#pragma unroll
        for (int e = 0; e < E; ++e) {
            p[e] = expf(logit[e] - mx);
            sum += p[e];
        }
        const float inv = 1.0f / sum;
#pragma unroll
        for (int e = 0; e < E; ++e) {
            float q = p[e] * inv;
            q = fminf(fmaxf(q, 1e-6f), 1.0f);     // clip probs
            p[e] = q;
        }
        // top-2, strict > scan from index 0 => lowest index wins ties (jax)
        int i0 = 0; float v0 = p[0];
#pragma unroll
        for (int e = 1; e < E; ++e)
            if (p[e] > v0) { v0 = p[e]; i0 = e; }
        int i1 = -1; float v1 = -1.0f;
#pragma unroll
        for (int e = 0; e < E; ++e) {
            if (e == i0) continue;
            if (p[e] > v1) { v1 = p[e]; i1 = e; }
        }
        const float norm = 1.0f / (v0 + v1 + 1e-8f);
        out[b * 2 + 0] = v0 * norm;
        out[b * 2 + 1] = v1 * norm;
        out[128 + b * 2 + 0] = (float)i0;
        out[128 + b * 2 + 1] = (float)i1;
    }
}

// ---------------------------------------------------------------------------
// Kernel 3: counts -> usage EMA -> bias update -> loss. Single block.
// Output layout: [256]=loss, [257:273]=new_usage_ema, [273:289]=new_expert_bias
// ---------------------------------------------------------------------------
__global__ __launch_bounds__(64) void finalize_kernel(const float* __restrict__ expert_bias,
                                                      const float* __restrict__ usage_ema,
                                                      float* __restrict__ out) {
    const int e = threadIdx.x;
    if (e < E) {
        float cnt = 0.f;
        for (int i = 0; i < B * TOPK; ++i) {
            if ((int)out[128 + i] == e) cnt += 1.f;
        }
        const float usage = cnt * (1.0f / (B * TOPK));
        const float new_ema = 0.9f * usage_ema[e] + 0.1f * usage;
        const float imb = new_ema - (1.0f / E);
        float nb = expert_bias[e] - 0.01f * imb;
        nb = fminf(fmaxf(nb, -5.0f), 5.0f);
        out[257 + e] = new_ema;
        out[273 + e] = nb;
    }
    if (e == 0) out[256] = 0.0f;  // load_balance_loss
}

// ---------------------------------------------------------------------------
extern "C" void kernel_launch(void* const* d_in, const int* in_sizes, int n_in,
                              void* d_out, int out_size, void* d_ws, size_t ws_size,
                              hipStream_t stream) {
    const float* x           = (const float*)d_in[0];
    const float* gate_w      = (const float*)d_in[1];
    const float* gate_b      = (const float*)d_in[2];
    const float* expert_bias = (const float*)d_in[3];
    const float* usage_ema   = (const float*)d_in[4];
    float* out = (float*)d_out;
    float* pooled = (float*)d_ws;                 // B*C floats = 256 KB scratch

    pool_kernel<<<B * C, 256, 0, stream>>>(x, pooled);
    gate_kernel<<<B, 256, 0, stream>>>(pooled, gate_w, gate_b, expert_bias, out);
    finalize_kernel<<<1, 64, 0, stream>>>(expert_bias, usage_ema, out);
}

// Round 3
// 169.938 us; speedup vs baseline: 1.1064x; 1.1064x over previous
//
#include <hip/hip_runtime.h>

#define B 64
#define C 1024
#define HW 4096          // 64*64
#define E 16
#define TOPK 2

typedef float f4 __attribute__((ext_vector_type(4)));

// d_ws layout (floats):
//   [0, B*C)        pooled
//   [B*C, B*C+16)   counts (float, atomicAdd accumulated)
//   [B*C+16]        arrival counter (uint)

// ---------------------------------------------------------------------------
// Kernel 1: pooled[b,c] = mean over HW of x[b,c,:,:]
// One block (256 threads) per row of 4096 floats. Non-temporal float4 loads
// (x is streamed once, no reuse -> skip L2 pollution).
// Block 0 also zeros the counts/counter scratch for kernel 2.
// ---------------------------------------------------------------------------
__global__ __launch_bounds__(256) void pool_kernel(const float* __restrict__ x,
                                                   float* __restrict__ pooled,
                                                   float* __restrict__ counts,
                                                   unsigned int* __restrict__ counter) {
    const int row = blockIdx.x;                   // 0 .. B*C-1
    const int t = threadIdx.x;                    // 0..255

    if (row == 0) {                               // zero scratch for gate kernel
        if (t < E) counts[t] = 0.0f;
        if (t == E) *counter = 0u;
    }

    const f4* xr = reinterpret_cast<const f4*>(x + (size_t)row * HW);
    float s = 0.f;
#pragma unroll
    for (int k = 0; k < 4; ++k) {                 // 4 * 256 float4 = 4096 floats
        f4 v = __builtin_nontemporal_load(xr + t + k * 256);
        s += (v.x + v.y) + (v.z + v.w);
    }

    // wave (64-lane) reduction
#pragma unroll
    for (int off = 32; off > 0; off >>= 1)
        s += __shfl_down(s, off, 64);

    __shared__ float ws[4];
    const int lane = t & 63, wid = t >> 6;
    if (lane == 0) ws[wid] = s;
    __syncthreads();
    if (t == 0) {
        float tot = (ws[0] + ws[1]) + (ws[2] + ws[3]);
        pooled[row] = tot * (1.0f / HW);
    }
}

// ---------------------------------------------------------------------------
// Kernel 2: per-batch gating + fused finalize (last-block pattern).
// logits = pooled @ gate_w^T + gate_b; clip; +expert_bias; softmax; clip;
// top-2 (strict > scan => lowest index wins ties, matching jax); renorm.
// Writes probs -> out[0:128], indices(float) -> out[128:256].
// Expert counts via device-scope atomicAdd; last arriving block computes
// EMA + bias update (out[256]=loss, [257:273)=ema, [273:289)=bias).
// ---------------------------------------------------------------------------
__global__ __launch_bounds__(256) void gate_kernel(const float* __restrict__ pooled,
                                                   const float* __restrict__ gate_w,
                                                   const float* __restrict__ gate_b,
                                                   const float* __restrict__ expert_bias,
                                                   const float* __restrict__ usage_ema,
                                                   float* __restrict__ out,
                                                   float* __restrict__ counts,
                                                   unsigned int* __restrict__ counter) {
    const int b = blockIdx.x;                     // 0..B-1
    const int t = threadIdx.x;                    // 0..255

    float acc[E];
#pragma unroll
    for (int e = 0; e < E; ++e) acc[e] = 0.f;

    const float* pr = pooled + b * C;
    for (int c = t; c < C; c += 256) {            // 4 iterations
        float p = pr[c];
#pragma unroll
        for (int e = 0; e < E; ++e)
            acc[e] += p * gate_w[e * C + c];
    }

    __shared__ float red[E][4];
    const int lane = t & 63, wid = t >> 6;
#pragma unroll
    for (int e = 0; e < E; ++e) {
        float v = acc[e];
#pragma unroll
        for (int off = 32; off > 0; off >>= 1)
            v += __shfl_down(v, off, 64);
        if (lane == 0) red[e][wid] = v;
    }
    __syncthreads();

    __shared__ int is_last;
    if (t == 0) {
        float logit[E];
        float mx = -1e30f;
#pragma unroll
        for (int e = 0; e < E; ++e) {
            float l = (red[e][0] + red[e][1]) + (red[e][2] + red[e][3]) + gate_b[e];
            l = fminf(fmaxf(l, -10.0f), 10.0f);   // clip logits
            l += expert_bias[e];
            logit[e] = l;
            mx = fmaxf(mx, l);
        }
        float p[E];
        float sum = 0.f;
#pragma unroll
        for (int e = 0; e < E; ++e) {
            p[e] = expf(logit[e] - mx);
            sum += p[e];
        }
        const float inv = 1.0f / sum;
#pragma unroll
        for (int e = 0; e < E; ++e) {
            float q = p[e] * inv;
            q = fminf(fmaxf(q, 1e-6f), 1.0f);     // clip probs
            p[e] = q;
        }
        // top-2, strict > scan from index 0 => lowest index wins ties (jax)
        int i0 = 0; float v0 = p[0];
#pragma unroll
        for (int e = 1; e < E; ++e)
            if (p[e] > v0) { v0 = p[e]; i0 = e; }
        int i1 = -1; float v1 = -1.0f;
#pragma unroll
        for (int e = 0; e < E; ++e) {
            if (e == i0) continue;
            if (p[e] > v1) { v1 = p[e]; i1 = e; }
        }
        const float norm = 1.0f / (v0 + v1 + 1e-8f);
        out[b * 2 + 0] = v0 * norm;
        out[b * 2 + 1] = v1 * norm;
        out[128 + b * 2 + 0] = (float)i0;
        out[128 + b * 2 + 1] = (float)i1;

        // expert usage counts (device-scope atomics: coherent across XCDs;
        // integer-valued adds -> order-independent -> deterministic)
        atomicAdd(&counts[i0], 1.0f);
        atomicAdd(&counts[i1], 1.0f);
        __threadfence();                          // release counts before arrival
        unsigned int old = atomicAdd(counter, 1u);
        is_last = (old == B - 1) ? 1 : 0;
    }
    __syncthreads();

    if (is_last) {
        __threadfence();                          // acquire
        if (t < E) {
            float cnt = atomicAdd(&counts[t], 0.0f);   // coherent atomic read
            const float usage = cnt * (1.0f / (B * TOPK));
            const float new_ema = 0.9f * usage_ema[t] + 0.1f * usage;
            const float imb = new_ema - (1.0f / E);
            float nb = expert_bias[t] - 0.01f * imb;
            nb = fminf(fmaxf(nb, -5.0f), 5.0f);
            out[257 + t] = new_ema;
            out[273 + t] = nb;
        }
        if (t == 0) out[256] = 0.0f;              // load_balance_loss
    }
}

// ---------------------------------------------------------------------------
extern "C" void kernel_launch(void* const* d_in, const int* in_sizes, int n_in,
                              void* d_out, int out_size, void* d_ws, size_t ws_size,
                              hipStream_t stream) {
    const float* x           = (const float*)d_in[0];
    const float* gate_w      = (const float*)d_in[1];
    const float* gate_b     = (const float*)d_in[2];
    const float* expert_bias = (const float*)d_in[3];
    const float* usage_ema   = (const float*)d_in[4];
    float* out = (float*)d_out;
    float* pooled = (float*)d_ws;                 // B*C floats
    float* counts = pooled + B * C;               // 16 floats
    unsigned int* counter = (unsigned int*)(counts + E);

    pool_kernel<<<B * C, 256, 0, stream>>>(x, pooled, counts, counter);
    gate_kernel<<<B, 256, 0, stream>>>(pooled, gate_w, gate_b, expert_bias,
                                       usage_ema, out, counts, counter);
}